// Round 8
// baseline (50.432 us; speedup 1.0000x reference)
//
#include <hip/hip_runtime.h>
#include <hip/hip_bf16.h>
#include <math.h>

// B=128, F_IN=1000, D=512, K=10, C=5, T=1000, TAU=0.1
// Contraction: logits_s[b,t,k] = sum_c v[b,c,t]*M[b,c,k], M = h @ W_mlp.
// R8: 4 nodes (per-node graph overhead measured ~6.5us; exec sum ~11us):
//   kA  (16 e-chunks x 20 k-splits) -> pA[20][128][512]   [weight-once, LDS]
//   kRA reduce 20 partials + bias + relu -> r_b; init hT[c][b][e] = b_ch
//   kB2 channel GEMM d-split [weight-once, LDS]; atomicAdd partials into hT
//   kCG phase1: waves 0-4 compute gate p[c] + M[c][k] from hT (relu inline);
//       phase2: per-t gumbel-sigmoid, softmax_c, MLP, softmax_k epilogue.

// ---- adapt partials ----
__global__ __launch_bounds__(256) void kA(const float* __restrict__ feats,
                                          const float* __restrict__ W_adapt,
                                          float* __restrict__ pA) {
    __shared__ float fls[128 * 50];   // [b][k] b-major
    __shared__ float wls[50 * 32];    // [k][e]
    const int tid = threadIdx.x;
    const int e0 = blockIdx.x * 32;
    const int s  = blockIdx.y;
    const int k0 = s * 50;

    #pragma unroll
    for (int it = 0; it < 25; ++it) {          // 6400 = 25*256
        int idx = it * 256 + tid;
        int b_l = idx / 50, k_l = idx - b_l * 50;
        fls[idx] = feats[b_l * 1000 + k0 + k_l];
    }
    #pragma unroll
    for (int it = 0; it < 7; ++it) {           // 1600 elems
        int idx = it * 256 + tid;
        if (idx < 1600)
            wls[idx] = W_adapt[(k0 + (idx >> 5)) * 512 + e0 + (idx & 31)];
    }
    __syncthreads();

    const int ep = tid & 15, bg = tid >> 4;    // 16 e-pairs x 16 b-groups
    float2 acc[8] = {};
    const float* fb = &fls[bg * 8 * 50];
    const float* wb = &wls[ep * 2];
    #pragma unroll 2
    for (int k = 0; k < 50; ++k) {
        float2 w = *(const float2*)&wb[k * 32];
        #pragma unroll
        for (int i = 0; i < 8; ++i) {
            float r = fb[i * 50 + k];          // LDS broadcast
            acc[i].x = fmaf(r, w.x, acc[i].x);
            acc[i].y = fmaf(r, w.y, acc[i].y);
        }
    }
    #pragma unroll
    for (int i = 0; i < 8; ++i)
        *(float2*)&pA[(s * 128 + bg * 8 + i) * 512 + e0 + ep * 2] = acc[i];
}

// ---- reduce 20 partials + bias + relu -> r_b; hT = channel bias ----
__global__ __launch_bounds__(256) void kRA(const float* __restrict__ pA,
                                           const float* __restrict__ b_adapt,
                                           const float* __restrict__ b_ch,
                                           float* __restrict__ r_b,
                                           float* __restrict__ hT) {
    int i = blockIdx.x * 256 + threadIdx.x;    // < 65536
    int e = i & 511;
    float acc = b_adapt[e];
    #pragma unroll
    for (int s = 0; s < 20; ++s) acc += pA[s * 65536 + i];
    r_b[i] = fmaxf(acc, 0.f);
    #pragma unroll
    for (int c = 0; c < 5; ++c) hT[c * 65536 + i] = b_ch[c * 512 + e];
}

// ---- channel GEMM, weight-once, atomic accumulate into hT ----
__global__ __launch_bounds__(256) void kB2(const float* __restrict__ r_b,
                                           const float* __restrict__ W_ch,
                                           float* __restrict__ hT) {
    __shared__ float rbs[128 * 64];   // [b][d]
    __shared__ float wls[64 * 32];    // [d][e]
    const int tid = threadIdx.x;
    const int e0 = blockIdx.x * 32;
    const int ds = blockIdx.y;
    const int c  = blockIdx.z;
    const int d0 = ds * 64;

    #pragma unroll
    for (int it = 0; it < 32; ++it) {          // 8192 = 32*256
        int idx = it * 256 + tid;
        rbs[idx] = r_b[(idx >> 6) * 512 + d0 + (idx & 63)];
    }
    #pragma unroll
    for (int it = 0; it < 8; ++it) {           // 2048 = 8*256
        int idx = it * 256 + tid;
        wls[idx] = W_ch[((size_t)(c * 512 + d0 + (idx >> 5))) * 512 + e0 + (idx & 31)];
    }
    __syncthreads();

    const int ep = tid & 15, bg = tid >> 4;
    float2 acc[8] = {};
    const float* rb = &rbs[bg * 8 * 64];
    const float* wb = &wls[ep * 2];
    #pragma unroll 2
    for (int d = 0; d < 64; ++d) {
        float2 w = *(const float2*)&wb[d * 32];
        #pragma unroll
        for (int i = 0; i < 8; ++i) {
            float r = rb[i * 64 + d];          // LDS broadcast
            acc[i].x = fmaf(r, w.x, acc[i].x);
            acc[i].y = fmaf(r, w.y, acc[i].y);
        }
    }
    #pragma unroll
    for (int i = 0; i < 8; ++i) {
        float* dst = &hT[(c * 128 + bg * 8 + i) * 512 + e0 + ep * 2];
        atomicAdd(dst,     acc[i].x);
        atomicAdd(dst + 1, acc[i].y);
    }
}

// ---- fused gate/M + epilogue: grid (2 tc, 128 b) x 512 thr ----
__global__ __launch_bounds__(512) void kCG(const float* __restrict__ hT,
                                           const float* __restrict__ W_gate,
                                           const float* __restrict__ W_mlp,
                                           const float* __restrict__ b_gate,
                                           const float* __restrict__ b_mlp,
                                           const float* __restrict__ gumbel,
                                           float* __restrict__ out_rs,
                                           float* __restrict__ out_gt,
                                           float* __restrict__ out_pt) {
    __shared__ float sWm[5120];        // W_mlp [e][k]
    __shared__ float red[5][11];
    __shared__ float spv[5], sM[50];
    const int tid = threadIdx.x;
    const int tc = blockIdx.x, b = blockIdx.y;

    #pragma unroll
    for (int it = 0; it < 10; ++it) sWm[it * 512 + tid] = W_mlp[it * 512 + tid];
    __syncthreads();

    // phase 1: wave c (0-4) computes gate + M for channel c
    const int wv = tid >> 6, lane = tid & 63;
    if (wv < 5) {
        const int c = wv;
        float gs = 0.f, am[10] = {};
        #pragma unroll
        for (int i = 0; i < 8; ++i) {
            int e = i * 64 + lane;
            float h = fmaxf(hT[(c * 128 + b) * 512 + e], 0.f);
            gs = fmaf(h, W_gate[c * 512 + e], gs);
            const float* wm = &sWm[e * 10];
            #pragma unroll
            for (int k = 0; k < 10; ++k) am[k] = fmaf(h, wm[k], am[k]);
        }
        #pragma unroll
        for (int off = 32; off; off >>= 1) {
            gs += __shfl_xor(gs, off);
            #pragma unroll
            for (int k = 0; k < 10; ++k) am[k] += __shfl_xor(am[k], off);
        }
        if (lane == 0) {
            red[c][0] = gs;
            #pragma unroll
            for (int k = 0; k < 10; ++k) red[c][1 + k] = am[k];
        }
    }
    __syncthreads();
    if (tid < 5) {
        float pv = 1.f / (1.f + __expf(-(red[tid][0] + b_gate[tid])));
        spv[tid] = pv;
        if (tc == 0) out_pt[b * 5 + tid] = pv;
    }
    if (tid < 50) sM[tid] = red[tid / 10][1 + tid % 10];
    __syncthreads();

    // phase 2: epilogue, 500 t per block
    int t = tc * 500 + tid;
    if (tid >= 500) return;
    float ex[5], ssum = 0.f;
    #pragma unroll
    for (int c = 0; c < 5; ++c) {
        float2 gu = *(const float2*)&gumbel[(size_t)(((b * 5 + c) * 1000) + t) * 2];
        float arg = (2.f * spv[c] - 1.f + gu.y - gu.x) * 10.0f;  // /tau
        float gt  = 1.f / (1.f + __expf(-arg));
        out_gt[(b * 5 + c) * 1000 + t] = gt;
        float e = __expf(gt);
        ex[c] = e; ssum += e;
    }
    float inv = 1.f / ssum;
    float lg[10];
    #pragma unroll
    for (int k = 0; k < 10; ++k) lg[k] = b_mlp[k];
    #pragma unroll
    for (int c = 0; c < 5; ++c) {
        float v = ex[c] * inv;
        #pragma unroll
        for (int k = 0; k < 10; ++k) lg[k] = fmaf(v, sM[c * 10 + k], lg[k]);
    }
    float mx = 0.f;
    #pragma unroll
    for (int k = 0; k < 10; ++k) { lg[k] = fmaxf(lg[k], 0.f); mx = fmaxf(mx, lg[k]); }
    float se = 0.f;
    #pragma unroll
    for (int k = 0; k < 10; ++k) { lg[k] = __expf(lg[k] - mx); se += lg[k]; }
    float invs = 1.f / se;
    float2 outv[5];
    #pragma unroll
    for (int k = 0; k < 10; ++k) ((float*)outv)[k] = lg[k] * invs;
    float2* dst = (float2*)&out_rs[(size_t)t * 1280 + b * 10];
    #pragma unroll
    for (int j = 0; j < 5; ++j) dst[j] = outv[j];
}

extern "C" void kernel_launch(void* const* d_in, const int* in_sizes, int n_in,
                              void* d_out, int out_size, void* d_ws, size_t ws_size,
                              hipStream_t stream) {
    const float* feats   = (const float*)d_in[0];
    const float* W_adapt = (const float*)d_in[1];
    const float* b_adapt = (const float*)d_in[2];
    const float* W_ch    = (const float*)d_in[3];
    const float* b_ch    = (const float*)d_in[4];
    const float* W_gate  = (const float*)d_in[5];
    const float* b_gate  = (const float*)d_in[6];
    const float* W_mlp   = (const float*)d_in[7];
    const float* b_mlp   = (const float*)d_in[8];
    const float* gumbel  = (const float*)d_in[9];

    float* out    = (float*)d_out;
    float* out_rs = out;                  // (T,B,K)  1,280,000
    float* out_gt = out + 1280000;        // (B,C,T)    640,000
    float* out_pt = out + 1920000;        // (B,C,1)        640

    float* ws  = (float*)d_ws;
    float* pA  = ws;                      // 20*128*512 = 1,310,720
    float* r_b = pA + 1310720;            //  65,536
    float* hT  = r_b + 65536;             // 5*128*512 = 327,680

    kA <<<dim3(16, 20),   256, 0, stream>>>(feats, W_adapt, pA);
    kRA<<<256,            256, 0, stream>>>(pA, b_adapt, b_ch, r_b, hT);
    kB2<<<dim3(16, 8, 5), 256, 0, stream>>>(r_b, W_ch, hT);
    kCG<<<dim3(2, 128),   512, 0, stream>>>(hT, W_gate, W_mlp, b_gate, b_mlp,
                                            gumbel, out_rs, out_gt, out_pt);
}

// Round 9
// 42.118 us; speedup vs baseline: 1.1974x; 1.1974x over previous
//
#include <hip/hip_runtime.h>
#include <hip/hip_bf16.h>
#include <math.h>

// B=128, F_IN=1000, D=512, K=10, C=5, T=1000, TAU=0.1
// Contraction: logits_s[b,t,k] = sum_c v[b,c,t]*M[b,c,k], M = h @ W_mlp.
// R9: R7's proven 3 GEMM-side kernels (no atomics, plain partial stores)
//     + kG merged into the epilogue (phase-1 reduces pB directly).
//   kA  (16 e-chunks x 20 k-splits) -> pA[20][128][512]   [weight-once, LDS]
//   kRA reduce 20 partials + bias + relu -> r_b
//   kB  (16 e-chunks x 8 d-splits x 5 c) -> pB[8][5][128][512] [weight-once]
//   kCG phase1: waves 0-4 reduce pB -> h -> gate p[c], M[c][k] (dup x2 tc);
//       phase2: per-t gumbel-sigmoid, softmax_c, MLP, softmax_k.

// ---- adapt partials ----
__global__ __launch_bounds__(256) void kA(const float* __restrict__ feats,
                                          const float* __restrict__ W_adapt,
                                          float* __restrict__ pA) {
    __shared__ float fls[128 * 50];   // [b][k] b-major
    __shared__ float wls[50 * 32];    // [k][e]
    const int tid = threadIdx.x;
    const int e0 = blockIdx.x * 32;
    const int s  = blockIdx.y;
    const int k0 = s * 50;

    #pragma unroll
    for (int it = 0; it < 25; ++it) {          // 6400 = 25*256
        int idx = it * 256 + tid;
        int b_l = idx / 50, k_l = idx - b_l * 50;
        fls[idx] = feats[b_l * 1000 + k0 + k_l];
    }
    #pragma unroll
    for (int it = 0; it < 7; ++it) {           // 1600 elems
        int idx = it * 256 + tid;
        if (idx < 1600)
            wls[idx] = W_adapt[(k0 + (idx >> 5)) * 512 + e0 + (idx & 31)];
    }
    __syncthreads();

    const int ep = tid & 15, bg = tid >> 4;    // 16 e-pairs x 16 b-groups
    float2 acc[8] = {};
    const float* fb = &fls[bg * 8 * 50];
    const float* wb = &wls[ep * 2];
    #pragma unroll 2
    for (int k = 0; k < 50; ++k) {
        float2 w = *(const float2*)&wb[k * 32];
        #pragma unroll
        for (int i = 0; i < 8; ++i) {
            float r = fb[i * 50 + k];          // LDS broadcast
            acc[i].x = fmaf(r, w.x, acc[i].x);
            acc[i].y = fmaf(r, w.y, acc[i].y);
        }
    }
    #pragma unroll
    for (int i = 0; i < 8; ++i)
        *(float2*)&pA[(s * 128 + bg * 8 + i) * 512 + e0 + ep * 2] = acc[i];
}

// ---- reduce 20 partials + bias + relu ----
__global__ __launch_bounds__(256) void kRA(const float* __restrict__ pA,
                                           const float* __restrict__ b_adapt,
                                           float* __restrict__ r_b) {
    int i = blockIdx.x * 256 + threadIdx.x;    // < 65536
    float acc = b_adapt[i & 511];
    #pragma unroll
    for (int s = 0; s < 20; ++s) acc += pA[s * 65536 + i];
    r_b[i] = fmaxf(acc, 0.f);
}

// ---- channel partials: pB[ds][c][b][e], weights fetched once ----
__global__ __launch_bounds__(256) void kB(const float* __restrict__ r_b,
                                          const float* __restrict__ W_ch,
                                          float* __restrict__ pB) {
    __shared__ float rbs[128 * 64];   // [b][d]
    __shared__ float wls[64 * 32];    // [d][e]
    const int tid = threadIdx.x;
    const int e0 = blockIdx.x * 32;
    const int ds = blockIdx.y;
    const int c  = blockIdx.z;
    const int d0 = ds * 64;

    #pragma unroll
    for (int it = 0; it < 32; ++it) {          // 8192 = 32*256
        int idx = it * 256 + tid;
        rbs[idx] = r_b[(idx >> 6) * 512 + d0 + (idx & 63)];
    }
    #pragma unroll
    for (int it = 0; it < 8; ++it) {           // 2048 = 8*256
        int idx = it * 256 + tid;
        wls[idx] = W_ch[((size_t)(c * 512 + d0 + (idx >> 5))) * 512 + e0 + (idx & 31)];
    }
    __syncthreads();

    const int ep = tid & 15, bg = tid >> 4;
    float2 acc[8] = {};
    const float* rb = &rbs[bg * 8 * 64];
    const float* wb = &wls[ep * 2];
    #pragma unroll 2
    for (int d = 0; d < 64; ++d) {
        float2 w = *(const float2*)&wb[d * 32];
        #pragma unroll
        for (int i = 0; i < 8; ++i) {
            float r = rb[i * 64 + d];          // LDS broadcast
            acc[i].x = fmaf(r, w.x, acc[i].x);
            acc[i].y = fmaf(r, w.y, acc[i].y);
        }
    }
    #pragma unroll
    for (int i = 0; i < 8; ++i)
        *(float2*)&pB[((ds * 5 + c) * 128 + bg * 8 + i) * 512 + e0 + ep * 2] = acc[i];
}

// ---- fused gate/M + epilogue: grid (2 tc, 128 b) x 512 thr ----
__global__ __launch_bounds__(512) void kCG(const float* __restrict__ pB,
                                           const float* __restrict__ b_ch,
                                           const float* __restrict__ W_gate,
                                           const float* __restrict__ W_mlp,
                                           const float* __restrict__ b_gate,
                                           const float* __restrict__ b_mlp,
                                           const float* __restrict__ gumbel,
                                           float* __restrict__ out_rs,
                                           float* __restrict__ out_gt,
                                           float* __restrict__ out_pt) {
    __shared__ float sWm[5120];        // W_mlp [e][k]
    __shared__ float red[5][11];
    __shared__ float spv[5], sM[50];
    const int tid = threadIdx.x;
    const int tc = blockIdx.x, b = blockIdx.y;

    #pragma unroll
    for (int it = 0; it < 10; ++it) sWm[it * 512 + tid] = W_mlp[it * 512 + tid];
    __syncthreads();

    // phase 1: wave c (0-4) computes gate + M for channel c (reduce 8 partials)
    const int wv = tid >> 6, lane = tid & 63;
    if (wv < 5) {
        const int c = wv;
        float gs = 0.f, am[10] = {};
        #pragma unroll
        for (int i = 0; i < 8; ++i) {
            int e = i * 64 + lane;
            float hs = b_ch[c * 512 + e];
            #pragma unroll
            for (int s = 0; s < 8; ++s)
                hs += pB[((s * 5 + c) * 128 + b) * 512 + e];
            float h = fmaxf(hs, 0.f);
            gs = fmaf(h, W_gate[c * 512 + e], gs);
            const float* wm = &sWm[e * 10];
            #pragma unroll
            for (int k = 0; k < 10; ++k) am[k] = fmaf(h, wm[k], am[k]);
        }
        #pragma unroll
        for (int off = 32; off; off >>= 1) {
            gs += __shfl_xor(gs, off);
            #pragma unroll
            for (int k = 0; k < 10; ++k) am[k] += __shfl_xor(am[k], off);
        }
        if (lane == 0) {
            red[c][0] = gs;
            #pragma unroll
            for (int k = 0; k < 10; ++k) red[c][1 + k] = am[k];
        }
    }
    __syncthreads();
    if (tid < 5) {
        float pv = 1.f / (1.f + __expf(-(red[tid][0] + b_gate[tid])));
        spv[tid] = pv;
        if (tc == 0) out_pt[b * 5 + tid] = pv;
    }
    if (tid < 50) sM[tid] = red[tid / 10][1 + tid % 10];
    __syncthreads();

    // phase 2: epilogue, 500 t per block
    int t = tc * 500 + tid;
    if (tid >= 500) return;
    float ex[5], ssum = 0.f;
    #pragma unroll
    for (int c = 0; c < 5; ++c) {
        float2 gu = *(const float2*)&gumbel[(size_t)(((b * 5 + c) * 1000) + t) * 2];
        float arg = (2.f * spv[c] - 1.f + gu.y - gu.x) * 10.0f;  // /tau
        float gt  = 1.f / (1.f + __expf(-arg));
        out_gt[(b * 5 + c) * 1000 + t] = gt;
        float e = __expf(gt);
        ex[c] = e; ssum += e;
    }
    float inv = 1.f / ssum;
    float lg[10];
    #pragma unroll
    for (int k = 0; k < 10; ++k) lg[k] = b_mlp[k];
    #pragma unroll
    for (int c = 0; c < 5; ++c) {
        float v = ex[c] * inv;
        #pragma unroll
        for (int k = 0; k < 10; ++k) lg[k] = fmaf(v, sM[c * 10 + k], lg[k]);
    }
    float mx = 0.f;
    #pragma unroll
    for (int k = 0; k < 10; ++k) { lg[k] = fmaxf(lg[k], 0.f); mx = fmaxf(mx, lg[k]); }
    float se = 0.f;
    #pragma unroll
    for (int k = 0; k < 10; ++k) { lg[k] = __expf(lg[k] - mx); se += lg[k]; }
    float invs = 1.f / se;
    float2 outv[5];
    #pragma unroll
    for (int k = 0; k < 10; ++k) ((float*)outv)[k] = lg[k] * invs;
    float2* dst = (float2*)&out_rs[(size_t)t * 1280 + b * 10];
    #pragma unroll
    for (int j = 0; j < 5; ++j) dst[j] = outv[j];
}

extern "C" void kernel_launch(void* const* d_in, const int* in_sizes, int n_in,
                              void* d_out, int out_size, void* d_ws, size_t ws_size,
                              hipStream_t stream) {
    const float* feats   = (const float*)d_in[0];
    const float* W_adapt = (const float*)d_in[1];
    const float* b_adapt = (const float*)d_in[2];
    const float* W_ch    = (const float*)d_in[3];
    const float* b_ch    = (const float*)d_in[4];
    const float* W_gate  = (const float*)d_in[5];
    const float* b_gate  = (const float*)d_in[6];
    const float* W_mlp   = (const float*)d_in[7];
    const float* b_mlp   = (const float*)d_in[8];
    const float* gumbel  = (const float*)d_in[9];

    float* out    = (float*)d_out;
    float* out_rs = out;                  // (T,B,K)  1,280,000
    float* out_gt = out + 1280000;        // (B,C,T)    640,000
    float* out_pt = out + 1920000;        // (B,C,1)        640

    float* ws  = (float*)d_ws;
    float* pA  = ws;                      // 20*128*512  = 1,310,720
    float* pB  = pA + 1310720;            // 8*5*128*512 = 2,621,440
    float* r_b = pB + 2621440;            //    65,536

    kA <<<dim3(16, 20),   256, 0, stream>>>(feats, W_adapt, pA);
    kRA<<<256,            256, 0, stream>>>(pA, b_adapt, r_b);
    kB <<<dim3(16, 8, 5), 256, 0, stream>>>(r_b, W_ch, pB);
    kCG<<<dim3(2, 128),   512, 0, stream>>>(pB, b_ch, W_gate, W_mlp, b_gate,
                                            b_mlp, gumbel, out_rs, out_gt, out_pt);
}